// Round 1
// 397.656 us; speedup vs baseline: 1.0840x; 1.0840x over previous
//
#include <hip/hip_runtime.h>

typedef unsigned short ushort;
typedef __attribute__((ext_vector_type(8))) short short8;
typedef __attribute__((ext_vector_type(8))) unsigned short ushort8;
typedef __attribute__((ext_vector_type(4))) unsigned short ushort4v;
typedef __attribute__((ext_vector_type(4))) float fx4;

#define MAXNNZ (256*7)

__device__ __forceinline__ ushort f2bf(float f) {
    union { float f; unsigned u; } v; v.f = f;
    unsigned r = v.u + 0x7fffu + ((v.u >> 16) & 1u);
    return (ushort)(r >> 16);
}

__device__ __forceinline__ float bf2f(ushort b) {
    union { unsigned u; float f; } v; v.u = ((unsigned)b) << 16;
    return v.f;
}

// async global->LDS, 16B per lane; LDS dest = wave-uniform base + lane*16
__device__ __forceinline__ void gload_lds16(const ushort* g, ushort* l) {
    __builtin_amdgcn_global_load_lds(
        (const __attribute__((address_space(1))) unsigned int*)g,
        (__attribute__((address_space(3))) unsigned int*)l, 16, 0, 0);
}

// ---------------- top-7 per row of coeff (rows 0..255), emit COO for cols<256 -----
__global__ __launch_bounds__(256)
void topk_kernel(const float* __restrict__ coeff,
                 int* __restrict__ coo_cnt, int* __restrict__ coo_m,
                 int* __restrict__ coo_p, float* __restrict__ coo_v)
{
    int row = blockIdx.x;            // = m index, 0..255
    int tid = threadIdx.x;
    const float* crow = coeff + (long)row * 2048;
    float av[8];
#pragma unroll
    for (int i = 0; i < 8; ++i) av[i] = fabsf(crow[tid + 256 * i]);
    __shared__ unsigned long long red[256];
    for (int t = 0; t < 7; ++t) {
        float mx = -1.f; int mi = 0;
#pragma unroll
        for (int i = 0; i < 8; ++i) if (av[i] > mx) { mx = av[i]; mi = i; }
        unsigned col = (unsigned)(tid + 256 * mi);
        unsigned long long pk = ((unsigned long long)__float_as_uint(mx) << 32)
                              | (unsigned long long)(2048u - col); // tie -> smaller col
        red[tid] = pk; __syncthreads();
        for (int s = 128; s > 0; s >>= 1) {
            if (tid < s) { if (red[tid + s] > red[tid]) red[tid] = red[tid + s]; }
            __syncthreads();
        }
        unsigned long long w = red[0];
        __syncthreads();
        unsigned wcol = 2048u - (unsigned)(w & 0xffffffffu);
        if ((wcol & 255u) == (unsigned)tid) av[wcol >> 8] = -1.f; // consume
        if (tid == 0 && wcol < 256u) {
            int pos = atomicAdd(coo_cnt, 1);
            coo_m[pos] = row; coo_p[pos] = (int)wcol; coo_v[pos] = crow[wcol];
        }
    }
}

// ---------------- COO -> CSC (single block) ----------------
__global__ __launch_bounds__(256)
void csc_kernel(const int* __restrict__ coo_cnt, const int* __restrict__ coo_m,
                const int* __restrict__ coo_p, const float* __restrict__ coo_v,
                int* __restrict__ csc_ptr, int* __restrict__ csc_m, float* __restrict__ csc_v)
{
    __shared__ int cnt[256];
    __shared__ int off[257];
    __shared__ int cur[256];
    int tid = threadIdx.x;
    cnt[tid] = 0;
    __syncthreads();
    int n = *coo_cnt; if (n > MAXNNZ) n = MAXNNZ;
    for (int e = tid; e < n; e += 256) atomicAdd(&cnt[coo_p[e]], 1);
    __syncthreads();
    if (tid == 0) {
        int s = 0;
        for (int p = 0; p < 256; ++p) { off[p] = s; s += cnt[p]; }
        off[256] = s;
    }
    __syncthreads();
    csc_ptr[tid] = off[tid];
    if (tid == 0) csc_ptr[256] = off[256];
    cur[tid] = off[tid];
    __syncthreads();
    for (int e = tid; e < n; e += 256) {
        int p = coo_p[e];
        int pos = atomicAdd(&cur[p], 1);
        csc_m[pos] = coo_m[e];
        csc_v[pos] = coo_v[e];
    }
}

// ---------------- fp32 -> bf16 convert, 4 tensors in one launch ----------------
__global__ void cvt4_kernel(const float* a0, ushort* d0, int n0,
                            const float* a1, ushort* d1, int n1,
                            const float* a2, ushort* d2, int n2,
                            const float* a3, ushort* d3, int n3)
{
    const float* s; ushort* d; int n;
    switch (blockIdx.y) {
        case 0: s = a0; d = d0; n = n0; break;
        case 1: s = a1; d = d1; n = n1; break;
        case 2: s = a2; d = d2; n = n2; break;
        default: s = a3; d = d3; n = n3; break;
    }
    int nv = n >> 2;
    for (int i = blockIdx.x * blockDim.x + threadIdx.x; i < nv; i += gridDim.x * blockDim.x) {
        fx4 v = ((const fx4*)s)[i];
        ushort4v o;
        o[0] = f2bf(v[0]); o[1] = f2bf(v[1]); o[2] = f2bf(v[2]); o[3] = f2bf(v[3]);
        ((ushort4v*)d)[i] = o;
    }
}

// ---------------- transpose f32 [z][R][C] -> bf16 [z][C][R] ----------------
__global__ __launch_bounds__(256)
void transpose_f32_bf16(const float* __restrict__ in, ushort* __restrict__ out, int R, int C)
{
    int z = blockIdx.z;
    const float* ib = in + (long)z * R * C;
    ushort* ob = out + (long)z * R * C;
    __shared__ ushort tile[64][72];
    int r0 = blockIdx.x * 64, c0 = blockIdx.y * 64;
    int tid = threadIdx.x;
    int rl = tid >> 2, sg = tid & 3;
#pragma unroll
    for (int h = 0; h < 4; ++h) {
        fx4 v = *(const fx4*)(ib + (long)(r0 + rl) * C + c0 + h * 16 + sg * 4);
#pragma unroll
        for (int i = 0; i < 4; ++i) tile[h * 16 + sg * 4 + i][rl] = f2bf(v[i]);
    }
    __syncthreads();
    int cl = rl;
#pragma unroll
    for (int h = 0; h < 2; ++h) {
        ushort8 vv = *(const ushort8*)(&tile[cl][h * 32 + sg * 8]);
        *(ushort8*)(ob + (long)(c0 + cl) * R + r0 + h * 32 + sg * 8) = vv;
    }
}

// ---------------- K-combine: ktc[z][p][d] = sum_e csc_v[e] * kbT[z][m_e][d] --------
__global__ __launch_bounds__(256)
void kcomb_kernel(const ushort* __restrict__ kbT, ushort* __restrict__ ktc,
                  const int* __restrict__ csc_ptr, const int* __restrict__ csc_m,
                  const float* __restrict__ csc_v)
{
    int z = blockIdx.y;
    int tid = threadIdx.x;
    int p = blockIdx.x * 64 + (tid >> 2);
    int d0 = (tid & 3) * 64;
    const ushort* src = kbT + (long)z * 65536;
    float acc[64];
#pragma unroll
    for (int i = 0; i < 64; ++i) acc[i] = 0.f;
    int e0 = csc_ptr[p], e1 = csc_ptr[p + 1];
    for (int e = e0; e < e1; ++e) {
        const ushort* row = src + csc_m[e] * 256 + d0;
        float c = csc_v[e];
#pragma unroll
        for (int u = 0; u < 8; ++u) {
            ushort8 v = *(const ushort8*)(row + u * 8);
#pragma unroll
            for (int t = 0; t < 8; ++t) acc[u * 8 + t] += bf2f(v[t]) * c;
        }
    }
    ushort* dst = ktc + (long)z * 65536 + (long)p * 256 + d0;
#pragma unroll
    for (int u = 0; u < 8; ++u) {
        ushort8 o;
#pragma unroll
        for (int t = 0; t < 8; ++t) o[t] = f2bf(acc[u * 8 + t]);
        *(ushort8*)(dst + u * 8) = o;
    }
}

// ---------------- 128x128-tile NT GEMM (kept for MODE 3 / PV) ----------
// MODE 3: PV batched (z grid): C bf16 obT, idx=(z>>3)*524288 + n2*2048 + (z&7)*256 + m
template<int MODE>
__global__ __launch_bounds__(256)
void gemm128(const ushort* __restrict__ A, long long strideA,
             const ushort* __restrict__ B, long long strideB,
             void* __restrict__ C,
             const float* __restrict__ bias0, const float* __restrict__ bias1,
             const float* __restrict__ bias2,
             int N, int K)
{
    int z = blockIdx.z;
    const ushort* Ab = A + (long long)z * strideA;
    const ushort* Bb = B + (long long)z * strideB;
    int m0 = blockIdx.x * 128, n0 = blockIdx.y * 128;

    __shared__ __align__(16) ushort As[128 * 32];
    __shared__ __align__(16) ushort Bs[128 * 32];
    __shared__ __align__(16) ushort Ct[(MODE == 3) ? 128 * 136 : 8];

    int tid = threadIdx.x;
    int wave = tid >> 6, lane = tid & 63;
    int wrow = wave >> 1, wcol = wave & 1;
    int l16 = lane & 15, quad = lane >> 4;
    int lrow = lane >> 2, lkq = lane & 3;

    fx4 acc[4][4];
#pragma unroll
    for (int i = 0; i < 4; ++i)
#pragma unroll
        for (int j = 0; j < 4; ++j) acc[i][j] = (fx4){0.f, 0.f, 0.f, 0.f};

    const ushort* gA0 = Ab + (long)(m0 + wave * 16 + lrow) * K + lkq * 8;
    const ushort* gA1 = gA0 + (long)64 * K;
    const ushort* gB0 = Bb + (long)(n0 + wave * 16 + lrow) * K + lkq * 8;
    const ushort* gB1 = gB0 + (long)64 * K;
    ushort* lA0 = As + (wave * 16) * 32;
    ushort* lA1 = As + (64 + wave * 16) * 32;
    ushort* lB0 = Bs + (wave * 16) * 32;
    ushort* lB1 = Bs + (64 + wave * 16) * 32;

    for (int kc = 0; kc < K; kc += 32) {
        __syncthreads();
        gload_lds16(gA0 + kc, lA0);
        gload_lds16(gA1 + kc, lA1);
        gload_lds16(gB0 + kc, lB0);
        gload_lds16(gB1 + kc, lB1);
        __syncthreads();

        short8 af[4], bf[4];
#pragma unroll
        for (int i = 0; i < 4; ++i)
            af[i] = *(const short8*)(As + (wrow * 64 + i * 16 + l16) * 32 + quad * 8);
#pragma unroll
        for (int j = 0; j < 4; ++j)
            bf[j] = *(const short8*)(Bs + (wcol * 64 + j * 16 + l16) * 32 + quad * 8);
#pragma unroll
        for (int i = 0; i < 4; ++i)
#pragma unroll
            for (int j = 0; j < 4; ++j)
                acc[i][j] = __builtin_amdgcn_mfma_f32_16x16x32_bf16(af[i], bf[j], acc[i][j], 0, 0, 0);
    }

    if (MODE == 3) {
        // orientation [n][m]: dest contiguous in m
#pragma unroll
        for (int i = 0; i < 4; ++i)
#pragma unroll
            for (int j = 0; j < 4; ++j) {
                int ml = wrow * 64 + i * 16 + quad * 4;
                int nl = wcol * 64 + j * 16 + l16;
                ushort4v pk;
#pragma unroll
                for (int r = 0; r < 4; ++r) pk[r] = f2bf(acc[i][j][r]);
                *(ushort4v*)(Ct + nl * 136 + ml) = pk;
            }
        __syncthreads();
        long long zb = z >> 3; int zh = z & 7;
        int nl = tid >> 3, mc = (tid & 7) * 16;
#pragma unroll
        for (int p4 = 0; p4 < 4; ++p4) {
            int n = p4 * 32 + nl;
            ushort8 v0 = *(const ushort8*)(Ct + n * 136 + mc);
            ushort8 v1 = *(const ushort8*)(Ct + n * 136 + mc + 8);
            ushort* dst = (ushort*)C + zb * 524288 + (long)(n0 + n) * 2048
                        + zh * 256 + m0 + mc;
            *(ushort8*)dst = v0;
            *(ushort8*)(dst + 8) = v1;
        }
        return;
    }
}

// ---------------- 256x256-tile NT GEMM, 8 waves, 4-deep pipelined LDS --------------
// Counted vmcnt (steady-state 12 = 3 K-tiles in flight), raw s_barrier, setprio,
// XCD-swizzled 1D grid. BK=32 => 64B LDS rows => conflict-free ds_read_b128.
// MODE 4: merged QKV, A=[6144][512] wqkv, B=[8192][512] xT; sec = m0>>11 uniform.
//         q/k: [sec][b][h][n][d] (re-tile via LDS, contiguous-in-d);
//         v:   [b][2048][256]    (re-tile via LDS, contiguous-in-n).
// MODE 5: final: A=[2048][2048] wob, B=[8192][2048] obT; f32 out + bias (direct).
template<int MODE>
__global__ __launch_bounds__(512, 2)
void gemm256(const ushort* __restrict__ A, const ushort* __restrict__ B,
             void* __restrict__ C,
             const float* __restrict__ bias0, const float* __restrict__ bias1,
             const float* __restrict__ bias2,
             int MT, int K)
{
    __shared__ __align__(16) ushort lds[4][2][8192];   // 128 KiB: 4 bufs x (A,B) x 256x32 bf16

    int nwg = gridDim.x;
    int bid = blockIdx.x;
    int cpx = nwg >> 3;                        // nwg % 8 == 0 guaranteed by launch
    int swz = (bid & 7) * cpx + (bid >> 3);    // XCD-aware swizzle (bijective)
    int mt = swz % MT, nt = swz / MT;
    int m0 = mt << 8, n0 = nt << 8;

    int tid = threadIdx.x;
    int wave = tid >> 6, lane = tid & 63;
    int wr = wave >> 2, wc = wave & 3;         // 2x4 wave grid; per-wave C = 128x64
    int l16 = lane & 15, quad = lane >> 4;

    // staging: slot s = wave*64+lane (rows 0..127) and +512 (rows 128..255);
    // row = s>>2, 16B chunk = s&3. LDS dest = wave-uniform base + lane*16.
    const ushort* gA0 = A + (long long)(m0 + wave * 16 + (lane >> 2)) * K + (lane & 3) * 8;
    const ushort* gA1 = gA0 + (long long)128 * K;
    const ushort* gB0 = B + (long long)(n0 + wave * 16 + (lane >> 2)) * K + (lane & 3) * 8;
    const ushort* gB1 = gB0 + (long long)128 * K;
    int ldso = wave * 512;                     // ushorts: wave's 1KB stripe

    fx4 acc[8][4];
#pragma unroll
    for (int i = 0; i < 8; ++i)
#pragma unroll
        for (int j = 0; j < 4; ++j) acc[i][j] = (fx4){0.f, 0.f, 0.f, 0.f};

    auto stage = [&](int b, int kc) {
        gload_lds16(gA0 + kc, &lds[b][0][ldso]);
        gload_lds16(gA1 + kc, &lds[b][0][4096 + ldso]);
        gload_lds16(gB0 + kc, &lds[b][1][ldso]);
        gload_lds16(gB1 + kc, &lds[b][1][4096 + ldso]);
    };
    auto compute = [&](int b) {
        short8 af[8], bf[4];
#pragma unroll
        for (int i = 0; i < 8; ++i)
            af[i] = *(const short8*)(&lds[b][0][(wr * 128 + i * 16 + l16) * 32 + quad * 8]);
#pragma unroll
        for (int j = 0; j < 4; ++j)
            bf[j] = *(const short8*)(&lds[b][1][(wc * 64 + j * 16 + l16) * 32 + quad * 8]);
        __builtin_amdgcn_s_setprio(1);
#pragma unroll
        for (int i = 0; i < 8; ++i)
#pragma unroll
            for (int j = 0; j < 4; ++j)
                acc[i][j] = __builtin_amdgcn_mfma_f32_16x16x32_bf16(af[i], bf[j], acc[i][j], 0, 0, 0);
        __builtin_amdgcn_s_setprio(0);
    };

    int NT = K >> 5;                           // K-tiles of 32; NT >= 4 for all uses
    stage(0, 0); stage(1, 32); stage(2, 64);   // 3-deep prologue (12 loads in flight)
    int kt = 0;
    for (; kt + 3 < NT; ++kt) {
        stage((kt + 3) & 3, (kt + 3) << 5);    // overwrites buf (kt-1)&3: reads done
        asm volatile("s_waitcnt vmcnt(12)" ::: "memory");  // tile kt landed, 3 in flight
        __builtin_amdgcn_s_barrier();
        asm volatile("" ::: "memory");
        compute(kt & 3);
        asm volatile("" ::: "memory");
        __builtin_amdgcn_s_barrier();
    }
    // drain: tiles NT-3, NT-2, NT-1
    asm volatile("s_waitcnt vmcnt(8)" ::: "memory");
    __builtin_amdgcn_s_barrier();
    asm volatile("" ::: "memory");
    compute(kt & 3); ++kt;
    asm volatile("" ::: "memory");
    __builtin_amdgcn_s_barrier();
    asm volatile("s_waitcnt vmcnt(4)" ::: "memory");
    __builtin_amdgcn_s_barrier();
    asm volatile("" ::: "memory");
    compute(kt & 3); ++kt;
    asm volatile("" ::: "memory");
    __builtin_amdgcn_s_barrier();
    asm volatile("s_waitcnt vmcnt(0)" ::: "memory");
    __builtin_amdgcn_s_barrier();
    asm volatile("" ::: "memory");
    compute(kt & 3);
    __builtin_amdgcn_s_barrier();

    if (MODE == 5) {
        // direct f32 stores + bias: 16 lanes cover 16 consecutive n -> 64B lines
        float* Cf = (float*)C + (long long)nt * 524288;
#pragma unroll
        for (int i = 0; i < 8; ++i) {
            int m = m0 + wr * 128 + i * 16 + quad * 4;
#pragma unroll
            for (int j = 0; j < 4; ++j) {
                int n = wc * 64 + j * 16 + l16;
                float* dst = Cf + (long long)m * 256 + n;
#pragma unroll
                for (int r = 0; r < 4; ++r)
                    dst[(long)r * 256] = acc[i][j][r] + bias0[m + r];
            }
        }
        return;
    }

    if (MODE == 4) {
        int sec = m0 >> 11;                    // block-uniform: 0=q, 1=k, 2=v
        int ms0 = m0 & 2047;
        ushort* ct = &lds[0][0][0];            // re-tile buffer: 128 x 264 ushorts
        if (sec < 2) {
            const float* bs = (sec == 0) ? bias0 : bias1;
            ushort* base = (ushort*)C + (long long)sec * 16777216
                         + (long long)nt * 524288 + (long long)(ms0 >> 8) * 65536;
#pragma unroll
            for (int hh = 0; hh < 2; ++hh) {   // n-halves; waves wc>>1==hh own half
                if ((wc >> 1) == hh) {
#pragma unroll
                    for (int i = 0; i < 8; ++i)
#pragma unroll
                        for (int j = 0; j < 4; ++j) {
                            int nl = (wc & 1) * 64 + j * 16 + l16;
                            int ml = wr * 128 + i * 16 + quad * 4;
                            ushort4v pk;
#pragma unroll
                            for (int r = 0; r < 4; ++r)
                                pk[r] = f2bf(acc[i][j][r] + bs[ms0 + ml + r]);
                            *(ushort4v*)(ct + nl * 264 + ml) = pk;
                        }
                }
                __syncthreads();
                int row = tid & 127, c0 = (tid >> 7) * 64;
                ushort* dst = base + (long long)(hh * 128 + row) * 256 + c0;
                const ushort* src = ct + row * 264 + c0;
#pragma unroll
                for (int u = 0; u < 8; ++u)
                    *(ushort8*)(dst + u * 8) = *(const ushort8*)(src + u * 8);
                __syncthreads();
            }
        } else {
            ushort* base = (ushort*)C + 33554432LL + (long long)nt * 524288
                         + (long long)ms0 * 256;
#pragma unroll
            for (int hh = 0; hh < 2; ++hh) {   // m-halves; waves wr==hh own half
                if (wr == hh) {
#pragma unroll
                    for (int i = 0; i < 8; ++i)
#pragma unroll
                        for (int j = 0; j < 4; ++j) {
                            int nl = wc * 64 + j * 16 + l16;
                            int ml = i * 16 + quad * 4;
#pragma unroll
                            for (int r = 0; r < 4; ++r)
                                ct[(ml + r) * 264 + nl] =
                                    f2bf(acc[i][j][r] + bias2[ms0 + hh * 128 + ml + r]);
                        }
                }
                __syncthreads();
                int row = tid & 127, c0 = (tid >> 7) * 64;
                ushort* dst = base + (long long)(hh * 128 + row) * 256 + c0;
                const ushort* src = ct + row * 264 + c0;
#pragma unroll
                for (int u = 0; u < 8; ++u)
                    *(ushort8*)(dst + u * 8) = *(const ushort8*)(src + u * 8);
                __syncthreads();
            }
        }
        return;
    }
}

// ---------------- T = (Q^T K~)/s with fused softmax -> P bf16 [z][n][p] ------------
// block: 128 n-rows x full 256 p-cols; waves 2x2 (wrow: n-half, wcol: p-half)
__global__ __launch_bounds__(256)
void tsm_kernel(const ushort* __restrict__ Q, const ushort* __restrict__ Kt,
                ushort* __restrict__ P, const float* __restrict__ scale_src)
{
    int z = blockIdx.y;
    const ushort* Ab = Q + (long)z * 65536;    // [n][d]
    const ushort* Bb = Kt + (long)z * 65536;   // [p][d]
    int n0 = blockIdx.x * 128;

    __shared__ __align__(16) ushort As[128 * 32];
    __shared__ __align__(16) ushort Bs[256 * 32];
    __shared__ float rmax[2][128];
    __shared__ float rsum[2][128];

    int tid = threadIdx.x;
    int wave = tid >> 6, lane = tid & 63;
    int wrow = wave >> 1, wcol = wave & 1;
    int l16 = lane & 15, quad = lane >> 4;
    int lrow = lane >> 2, lkq = lane & 3;

    fx4 acc[4][8];
#pragma unroll
    for (int i = 0; i < 4; ++i)
#pragma unroll
        for (int j = 0; j < 8; ++j) acc[i][j] = (fx4){0.f, 0.f, 0.f, 0.f};

    const ushort* gA0 = Ab + (long)(n0 + wave * 16 + lrow) * 256 + lkq * 8;
    const ushort* gA1 = gA0 + 64 * 256;
    const ushort* gB0 = Bb + (long)(wave * 16 + lrow) * 256 + lkq * 8;
    ushort* lA0 = As + (wave * 16) * 32;
    ushort* lA1 = As + (64 + wave * 16) * 32;
    ushort* lB0 = Bs + (wave * 16) * 32;

    for (int kc = 0; kc < 256; kc += 32) {
        __syncthreads();
        gload_lds16(gA0 + kc, lA0);
        gload_lds16(gA1 + kc, lA1);
        gload_lds16(gB0 + kc, lB0);
        gload_lds16(gB0 + 64 * 256 + kc, lB0 + 64 * 32);
        gload_lds16(gB0 + 128 * 256 + kc, lB0 + 128 * 32);
        gload_lds16(gB0 + 192 * 256 + kc, lB0 + 192 * 32);
        __syncthreads();

        short8 af[4], bf[8];
#pragma unroll
        for (int i = 0; i < 4; ++i)
            af[i] = *(const short8*)(As + (wrow * 64 + i * 16 + l16) * 32 + quad * 8);
#pragma unroll
        for (int j = 0; j < 8; ++j)
            bf[j] = *(const short8*)(Bs + (wcol * 128 + j * 16 + l16) * 32 + quad * 8);
#pragma unroll
        for (int i = 0; i < 4; ++i)
#pragma unroll
            for (int j = 0; j < 8; ++j)
                acc[i][j] = __builtin_amdgcn_mfma_f32_16x16x32_bf16(af[i], bf[j], acc[i][j], 0, 0, 0);
    }

    float sc = 1.0f / scale_src[0];
#pragma unroll
    for (int i = 0; i < 4; ++i)
#pragma unroll
        for (int j = 0; j < 8; ++j)
#pragma unroll
            for (int r = 0; r < 4; ++r) acc[i][j][r] *= sc;

    // --- row max: local over j, shfl over l16 (16-lane groups), LDS over wcol ---
    float lm[4][4];
#pragma unroll
    for (int i = 0; i < 4; ++i)
#pragma unroll
        for (int r = 0; r < 4; ++r) {
            float m = -1e30f;
#pragma unroll
            for (int j = 0; j < 8; ++j) m = fmaxf(m, acc[i][j][r]);
            lm[i][r] = m;
        }
#pragma unroll
    for (int d = 1; d < 16; d <<= 1)
#pragma unroll
        for (int i = 0; i < 4; ++i)
#pragma unroll
            for (int r = 0; r < 4; ++r) lm[i][r] = fmaxf(lm[i][r], __shfl_xor(lm[i][r], d, 16));
    if (l16 == 0) {
#pragma unroll
        for (int i = 0; i < 4; ++i)
#pragma unroll
            for (int r = 0; r < 4; ++r)
                rmax[wcol][wrow * 64 + i * 16 + quad * 4 + r] = lm[i][r];
    }
    __syncthreads();

    // --- exp + row sum ---
    float ls[4][4];
#pragma unroll
    for (int i = 0; i < 4; ++i)
#pragma unroll
        for (int r = 0; r < 4; ++r) {
            int row = wrow * 64 + i * 16 + quad * 4 + r;
            float M = fmaxf(rmax[0][row], rmax[1][row]);
            float s = 0.f;
#pragma unroll
            for (int j = 0; j < 8; ++j) {
                float e = __expf(acc[i][j][r] - M);
                acc[i][j][r] = e;
                s += e;
            }
            ls[i][r] = s;
        }
#pragma unroll
    for (int d = 1; d < 16; d <<= 1)
#pragma unroll
        for (int i = 0; i < 4; ++i)
#pragma unroll
            for (int r = 0; r < 4; ++r) ls[i][r] += __shfl_xor(ls[i][r], d, 16);
    if (l16 == 0) {
#pragma unroll
        for (int i = 0; i < 4; ++i)
#pragma unroll
            for (int r = 0; r < 4; ++r)
                rsum[wcol][wrow * 64 + i * 16 + quad * 4 + r] = ls[i][r];
    }
    __syncthreads();

    // --- normalize + write P ---
    ushort* Pb = P + (long)z * 65536;
#pragma unroll
    for (int i = 0; i < 4; ++i)
#pragma unroll
        for (int r = 0; r < 4; ++r) {
            int row = wrow * 64 + i * 16 + quad * 4 + r;
            float inv = 1.0f / (rsum[0][row] + rsum[1][row]);
#pragma unroll
            for (int j = 0; j < 8; ++j)
                Pb[(long)(n0 + row) * 256 + wcol * 128 + j * 16 + l16] = f2bf(acc[i][j][r] * inv);
        }
}

extern "C" void kernel_launch(void* const* d_in, const int* in_sizes, int n_in,
                              void* d_out, int out_size, void* d_ws, size_t ws_size,
                              hipStream_t stream)
{
    const float* x     = (const float*)d_in[0];
    const float* Wq    = (const float*)d_in[1];
    const float* bq    = (const float*)d_in[2];
    const float* Wk    = (const float*)d_in[3];
    const float* bk    = (const float*)d_in[4];
    const float* Wv    = (const float*)d_in[5];
    const float* bv    = (const float*)d_in[6];
    const float* Wo    = (const float*)d_in[7];
    const float* bo    = (const float*)d_in[8];
    const float* coeff = (const float*)d_in[9];
    const float* scale = (const float*)d_in[10];
    float* out = (float*)d_out;

    size_t o = 0;
    char* w = (char*)d_ws;
    auto take = [&](size_t bytes) -> void* {
        void* p = w + o; o += (bytes + 255) & ~(size_t)255; return p;
    };
    int*    coo_cnt = (int*)take(4);
    int*    coo_m   = (int*)take(MAXNNZ * 4);
    int*    coo_p   = (int*)take(MAXNNZ * 4);
    float*  coo_v   = (float*)take(MAXNNZ * 4);
    int*    csc_ptr = (int*)take(257 * 4);
    int*    csc_m   = (int*)take(MAXNNZ * 4);
    float*  csc_v   = (float*)take(MAXNNZ * 4);
    ushort* wqkv = (ushort*)take(6144L * 512 * 2);       // [wq;wk;wv] stacked
    ushort* wob  = (ushort*)take(2048L * 2048 * 2);
    ushort* xT   = (ushort*)take(32L * 256 * 512 * 2);   // [b][n][cin] == [8192][512]
    ushort* qkv  = (ushort*)take(3 * 16777216L * 2);     // qbT | kbT | vb contiguous
    ushort* qbT = qkv;                                   // [b][h][n][d]
    ushort* kbT = qkv + 16777216L;                       // [b][h][m][d]
    ushort* vb  = qkv + 33554432L;                       // [b][2048][256]
    ushort* ktc = (ushort*)take(16777216L * 2);          // [z][p][d]
    // aliases (lifetimes disjoint):
    ushort* P_ws = kbT;   // kbT dead after kcomb; tsm writes P, PV reads it
    ushort* obT  = qbT;   // qbT dead after tsm; PV writes obT == [8192][2048], final reads
    (void)in_sizes; (void)n_in; (void)out_size; (void)ws_size;

    // 1) sparsity structure
    hipMemsetAsync(coo_cnt, 0, 4, stream);
    topk_kernel<<<256, 256, 0, stream>>>(coeff, coo_cnt, coo_m, coo_p, coo_v);
    csc_kernel<<<1, 256, 0, stream>>>(coo_cnt, coo_m, coo_p, coo_v, csc_ptr, csc_m, csc_v);

    // 2) weight converts + x transpose
    cvt4_kernel<<<dim3(1024, 4, 1), 256, 0, stream>>>(
        Wq, wqkv, 2048 * 512, Wk, wqkv + 2048L * 512, 2048 * 512,
        Wv, wqkv + 4096L * 512, 2048 * 512, Wo, wob, 2048 * 2048);
    transpose_f32_bf16<<<dim3(8, 4, 32), 256, 0, stream>>>(x, xT, 512, 256);

    // 3) merged QKV projection: [6144,512] x [8192,512]^T, 256^2 pipelined tiles
    gemm256<4><<<dim3(768, 1, 1), dim3(512, 1, 1), 0, stream>>>(
        wqkv, xT, qkv, bq, bk, bv, 24, 512);

    // 4) K-combine with sparse coeff: ktc[z][p][d]
    kcomb_kernel<<<dim3(4, 256), 256, 0, stream>>>(kbT, ktc, csc_ptr, csc_m, csc_v);

    // 5) T = (Q^T K~)/s, fused softmax -> P bf16 [z][n][p]
    tsm_kernel<<<dim3(2, 256), 256, 0, stream>>>(qbT, ktc, P_ws, scale);

    // 6) O[d][n] = sum_p V[d][p] P[n][p] -> obT [8192][2048]
    gemm128<3><<<dim3(2, 2, 256), 256, 0, stream>>>(
        vb, 65536, P_ws, 65536, obT, nullptr, nullptr, nullptr, 256, 256);

    // 7) merged final projection: [2048,2048] x [8192,2048]^T -> out f32 [b][2048][256]
    gemm256<5><<<dim3(256, 1, 1), dim3(512, 1, 1), 0, stream>>>(
        wob, obT, out, bo, nullptr, nullptr, 8, 2048);
}

// Round 2
// 386.288 us; speedup vs baseline: 1.1159x; 1.0294x over previous
//
#include <hip/hip_runtime.h>

typedef unsigned short ushort;
typedef __attribute__((ext_vector_type(8))) short short8;
typedef __attribute__((ext_vector_type(8))) unsigned short ushort8;
typedef __attribute__((ext_vector_type(4))) unsigned short ushort4v;
typedef __attribute__((ext_vector_type(4))) float fx4;

#define MAXNNZ (256*7)

__device__ __forceinline__ ushort f2bf(float f) {
    union { float f; unsigned u; } v; v.f = f;
    unsigned r = v.u + 0x7fffu + ((v.u >> 16) & 1u);
    return (ushort)(r >> 16);
}

__device__ __forceinline__ float bf2f(ushort b) {
    union { unsigned u; float f; } v; v.u = ((unsigned)b) << 16;
    return v.f;
}

// async global->LDS, 16B per lane; LDS dest = wave-uniform base + lane*16
__device__ __forceinline__ void gload_lds16(const ushort* g, ushort* l) {
    __builtin_amdgcn_global_load_lds(
        (const __attribute__((address_space(1))) unsigned int*)g,
        (__attribute__((address_space(3))) unsigned int*)l, 16, 0, 0);
}

// ---------------- top-7 per row of coeff (rows 0..255), emit COO for cols<256 -----
__global__ __launch_bounds__(256)
void topk_kernel(const float* __restrict__ coeff,
                 int* __restrict__ coo_cnt, int* __restrict__ coo_m,
                 int* __restrict__ coo_p, float* __restrict__ coo_v)
{
    int row = blockIdx.x;            // = m index, 0..255
    int tid = threadIdx.x;
    const float* crow = coeff + (long)row * 2048;
    float av[8];
#pragma unroll
    for (int i = 0; i < 8; ++i) av[i] = fabsf(crow[tid + 256 * i]);
    __shared__ unsigned long long red[256];
    for (int t = 0; t < 7; ++t) {
        float mx = -1.f; int mi = 0;
#pragma unroll
        for (int i = 0; i < 8; ++i) if (av[i] > mx) { mx = av[i]; mi = i; }
        unsigned col = (unsigned)(tid + 256 * mi);
        unsigned long long pk = ((unsigned long long)__float_as_uint(mx) << 32)
                              | (unsigned long long)(2048u - col); // tie -> smaller col
        red[tid] = pk; __syncthreads();
        for (int s = 128; s > 0; s >>= 1) {
            if (tid < s) { if (red[tid + s] > red[tid]) red[tid] = red[tid + s]; }
            __syncthreads();
        }
        unsigned long long w = red[0];
        __syncthreads();
        unsigned wcol = 2048u - (unsigned)(w & 0xffffffffu);
        if ((wcol & 255u) == (unsigned)tid) av[wcol >> 8] = -1.f; // consume
        if (tid == 0 && wcol < 256u) {
            int pos = atomicAdd(coo_cnt, 1);
            coo_m[pos] = row; coo_p[pos] = (int)wcol; coo_v[pos] = crow[wcol];
        }
    }
}

// ---------------- COO -> CSC (single block) ----------------
__global__ __launch_bounds__(256)
void csc_kernel(const int* __restrict__ coo_cnt, const int* __restrict__ coo_m,
                const int* __restrict__ coo_p, const float* __restrict__ coo_v,
                int* __restrict__ csc_ptr, int* __restrict__ csc_m, float* __restrict__ csc_v)
{
    __shared__ int cnt[256];
    __shared__ int off[257];
    __shared__ int cur[256];
    int tid = threadIdx.x;
    cnt[tid] = 0;
    __syncthreads();
    int n = *coo_cnt; if (n > MAXNNZ) n = MAXNNZ;
    for (int e = tid; e < n; e += 256) atomicAdd(&cnt[coo_p[e]], 1);
    __syncthreads();
    if (tid == 0) {
        int s = 0;
        for (int p = 0; p < 256; ++p) { off[p] = s; s += cnt[p]; }
        off[256] = s;
    }
    __syncthreads();
    csc_ptr[tid] = off[tid];
    if (tid == 0) csc_ptr[256] = off[256];
    cur[tid] = off[tid];
    __syncthreads();
    for (int e = tid; e < n; e += 256) {
        int p = coo_p[e];
        int pos = atomicAdd(&cur[p], 1);
        csc_m[pos] = coo_m[e];
        csc_v[pos] = coo_v[e];
    }
}

// ---------------- fp32 -> bf16 convert, 4 tensors in one launch ----------------
__global__ void cvt4_kernel(const float* a0, ushort* d0, int n0,
                            const float* a1, ushort* d1, int n1,
                            const float* a2, ushort* d2, int n2,
                            const float* a3, ushort* d3, int n3)
{
    const float* s; ushort* d; int n;
    switch (blockIdx.y) {
        case 0: s = a0; d = d0; n = n0; break;
        case 1: s = a1; d = d1; n = n1; break;
        case 2: s = a2; d = d2; n = n2; break;
        default: s = a3; d = d3; n = n3; break;
    }
    int nv = n >> 2;
    for (int i = blockIdx.x * blockDim.x + threadIdx.x; i < nv; i += gridDim.x * blockDim.x) {
        fx4 v = ((const fx4*)s)[i];
        ushort4v o;
        o[0] = f2bf(v[0]); o[1] = f2bf(v[1]); o[2] = f2bf(v[2]); o[3] = f2bf(v[3]);
        ((ushort4v*)d)[i] = o;
    }
}

// ---------------- transpose f32 [z][R][C] -> bf16 [z][C][R] ----------------
__global__ __launch_bounds__(256)
void transpose_f32_bf16(const float* __restrict__ in, ushort* __restrict__ out, int R, int C)
{
    int z = blockIdx.z;
    const float* ib = in + (long)z * R * C;
    ushort* ob = out + (long)z * R * C;
    __shared__ ushort tile[64][72];
    int r0 = blockIdx.x * 64, c0 = blockIdx.y * 64;
    int tid = threadIdx.x;
    int rl = tid >> 2, sg = tid & 3;
#pragma unroll
    for (int h = 0; h < 4; ++h) {
        fx4 v = *(const fx4*)(ib + (long)(r0 + rl) * C + c0 + h * 16 + sg * 4);
#pragma unroll
        for (int i = 0; i < 4; ++i) tile[h * 16 + sg * 4 + i][rl] = f2bf(v[i]);
    }
    __syncthreads();
    int cl = rl;
#pragma unroll
    for (int h = 0; h < 2; ++h) {
        ushort8 vv = *(const ushort8*)(&tile[cl][h * 32 + sg * 8]);
        *(ushort8*)(ob + (long)(c0 + cl) * R + r0 + h * 32 + sg * 8) = vv;
    }
}

// ---------------- K-combine: ktc[z][p][d] = sum_e csc_v[e] * kbT[z][m_e][d] --------
__global__ __launch_bounds__(256)
void kcomb_kernel(const ushort* __restrict__ kbT, ushort* __restrict__ ktc,
                  const int* __restrict__ csc_ptr, const int* __restrict__ csc_m,
                  const float* __restrict__ csc_v)
{
    int z = blockIdx.y;
    int tid = threadIdx.x;
    int p = blockIdx.x * 64 + (tid >> 2);
    int d0 = (tid & 3) * 64;
    const ushort* src = kbT + (long)z * 65536;
    float acc[64];
#pragma unroll
    for (int i = 0; i < 64; ++i) acc[i] = 0.f;
    int e0 = csc_ptr[p], e1 = csc_ptr[p + 1];
    for (int e = e0; e < e1; ++e) {
        const ushort* row = src + csc_m[e] * 256 + d0;
        float c = csc_v[e];
#pragma unroll
        for (int u = 0; u < 8; ++u) {
            ushort8 v = *(const ushort8*)(row + u * 8);
#pragma unroll
            for (int t = 0; t < 8; ++t) acc[u * 8 + t] += bf2f(v[t]) * c;
        }
    }
    ushort* dst = ktc + (long)z * 65536 + (long)p * 256 + d0;
#pragma unroll
    for (int u = 0; u < 8; ++u) {
        ushort8 o;
#pragma unroll
        for (int t = 0; t < 8; ++t) o[t] = f2bf(acc[u * 8 + t]);
        *(ushort8*)(dst + u * 8) = o;
    }
}

// ---------------- 128x128-tile NT GEMM (kept for MODE 3 / PV) ----------
// MODE 3: PV batched (z grid): C bf16 obT, idx=(z>>3)*524288 + n2*2048 + (z&7)*256 + m
template<int MODE>
__global__ __launch_bounds__(256)
void gemm128(const ushort* __restrict__ A, long long strideA,
             const ushort* __restrict__ B, long long strideB,
             void* __restrict__ C,
             const float* __restrict__ bias0, const float* __restrict__ bias1,
             const float* __restrict__ bias2,
             int N, int K)
{
    int z = blockIdx.z;
    const ushort* Ab = A + (long long)z * strideA;
    const ushort* Bb = B + (long long)z * strideB;
    int m0 = blockIdx.x * 128, n0 = blockIdx.y * 128;

    __shared__ __align__(16) ushort As[128 * 32];
    __shared__ __align__(16) ushort Bs[128 * 32];
    __shared__ __align__(16) ushort Ct[(MODE == 3) ? 128 * 136 : 8];

    int tid = threadIdx.x;
    int wave = tid >> 6, lane = tid & 63;
    int wrow = wave >> 1, wcol = wave & 1;
    int l16 = lane & 15, quad = lane >> 4;
    int lrow = lane >> 2, lkq = lane & 3;

    fx4 acc[4][4];
#pragma unroll
    for (int i = 0; i < 4; ++i)
#pragma unroll
        for (int j = 0; j < 4; ++j) acc[i][j] = (fx4){0.f, 0.f, 0.f, 0.f};

    const ushort* gA0 = Ab + (long)(m0 + wave * 16 + lrow) * K + lkq * 8;
    const ushort* gA1 = gA0 + (long)64 * K;
    const ushort* gB0 = Bb + (long)(n0 + wave * 16 + lrow) * K + lkq * 8;
    const ushort* gB1 = gB0 + (long)64 * K;
    ushort* lA0 = As + (wave * 16) * 32;
    ushort* lA1 = As + (64 + wave * 16) * 32;
    ushort* lB0 = Bs + (wave * 16) * 32;
    ushort* lB1 = Bs + (64 + wave * 16) * 32;

    for (int kc = 0; kc < K; kc += 32) {
        __syncthreads();
        gload_lds16(gA0 + kc, lA0);
        gload_lds16(gA1 + kc, lA1);
        gload_lds16(gB0 + kc, lB0);
        gload_lds16(gB1 + kc, lB1);
        __syncthreads();

        short8 af[4], bf[4];
#pragma unroll
        for (int i = 0; i < 4; ++i)
            af[i] = *(const short8*)(As + (wrow * 64 + i * 16 + l16) * 32 + quad * 8);
#pragma unroll
        for (int j = 0; j < 4; ++j)
            bf[j] = *(const short8*)(Bs + (wcol * 64 + j * 16 + l16) * 32 + quad * 8);
#pragma unroll
        for (int i = 0; i < 4; ++i)
#pragma unroll
            for (int j = 0; j < 4; ++j)
                acc[i][j] = __builtin_amdgcn_mfma_f32_16x16x32_bf16(af[i], bf[j], acc[i][j], 0, 0, 0);
    }

    if (MODE == 3) {
        // orientation [n][m]: dest contiguous in m
#pragma unroll
        for (int i = 0; i < 4; ++i)
#pragma unroll
            for (int j = 0; j < 4; ++j) {
                int ml = wrow * 64 + i * 16 + quad * 4;
                int nl = wcol * 64 + j * 16 + l16;
                ushort4v pk;
#pragma unroll
                for (int r = 0; r < 4; ++r) pk[r] = f2bf(acc[i][j][r]);
                *(ushort4v*)(Ct + nl * 136 + ml) = pk;
            }
        __syncthreads();
        long long zb = z >> 3; int zh = z & 7;
        int nl = tid >> 3, mc = (tid & 7) * 16;
#pragma unroll
        for (int p4 = 0; p4 < 4; ++p4) {
            int n = p4 * 32 + nl;
            ushort8 v0 = *(const ushort8*)(Ct + n * 136 + mc);
            ushort8 v1 = *(const ushort8*)(Ct + n * 136 + mc + 8);
            ushort* dst = (ushort*)C + zb * 524288 + (long)(n0 + n) * 2048
                        + zh * 256 + m0 + mc;
            *(ushort8*)dst = v0;
            *(ushort8*)(dst + 8) = v1;
        }
        return;
    }
}

// ---------------- 256x256-tile NT GEMM, 8 waves, fine-phase pipelined --------------
// 4-deep LDS ring (BK=32), 2 phases per K-tile:
//  Ph1: 8 swizzled ds_read_b128 + stage A(t+3) + bar + lgkm0 + 16 MFMA (prio1) + bar
//  Ph2: 4 reads           + stage B(t+3) + vmcnt(8) + bar + lgkm0 + 16 MFMA + bar
// Bank-conflict fix (rule #21): linear gload_lds dest + inverse-swizzled global
// source chunk (^ (slot>>3)&3) + swizzled read chunk (^ (l16>>1)&3).
// MODE 4: merged QKV, A=[6144][512] wqkv, B=[8192][512] xT; sec = m0>>11 uniform.
// MODE 5: final: A=[2048][2048] wob, B=[8192][2048] obT; f32 out + bias (direct).
template<int MODE>
__global__ __launch_bounds__(512, 2)
void gemm256(const ushort* __restrict__ A, const ushort* __restrict__ B,
             void* __restrict__ C,
             const float* __restrict__ bias0, const float* __restrict__ bias1,
             const float* __restrict__ bias2,
             int MT, int K)
{
    __shared__ __align__(16) ushort lds[4][2][8192];   // 128 KiB ring: 4 x (A,B) x 256x32

    int nwg = gridDim.x;
    int bid = blockIdx.x;
    int cpx = nwg >> 3;                        // nwg % 8 == 0 guaranteed by launch
    int swz = (bid & 7) * cpx + (bid >> 3);    // XCD-aware swizzle (bijective)
    int mt = swz % MT, nt = swz / MT;
    int m0 = mt << 8, n0 = nt << 8;

    int tid = threadIdx.x;
    int wave = tid >> 6, lane = tid & 63;
    int wr = wave >> 2, wc = wave & 3;         // 2x4 wave grid; per-wave C = 128x64
    int l16 = lane & 15, quad = lane >> 4;

    // staging source (inverse swizzle): slot = u*512 + wave*64 + lane; prow = slot>>2;
    // logical chunk = (lane&3) ^ ((slot>>3)&3) = (lane&3) ^ ((lane>>3)&3)
    int lc = (((lane & 3) ^ ((lane >> 3) & 3))) * 8;
    const ushort* gA0 = A + (long long)(m0 + wave * 16 + (lane >> 2)) * K + lc;
    const ushort* gA1 = gA0 + (long long)128 * K;
    const ushort* gB0 = B + (long long)(n0 + wave * 16 + (lane >> 2)) * K + lc;
    const ushort* gB1 = gB0 + (long long)128 * K;
    int ldso = wave * 512;                     // wave's 1KB stripe (ushorts)

    // read-side swizzle: chunk ^= (row>>1)&3, row ≡ l16 (mod 16-aligned bases)
    int rsw = ((l16 >> 1) & 3) * 8;
    int aoff = (wr * 128 + l16) * 32 + ((quad * 8) ^ rsw);
    int boff = (wc * 64 + l16) * 32 + ((quad * 8) ^ rsw);

    fx4 acc[8][4];
#pragma unroll
    for (int i = 0; i < 8; ++i)
#pragma unroll
        for (int j = 0; j < 4; ++j) acc[i][j] = (fx4){0.f, 0.f, 0.f, 0.f};

    auto stageA = [&](int b, int kc) {
        gload_lds16(gA0 + kc, &lds[b][0][ldso]);
        gload_lds16(gA1 + kc, &lds[b][0][4096 + ldso]);
    };
    auto stageB = [&](int b, int kc) {
        gload_lds16(gB0 + kc, &lds[b][1][ldso]);
        gload_lds16(gB1 + kc, &lds[b][1][4096 + ldso]);
    };

    short8 af[4], bf[4];
    auto readA = [&](int b, int half) {
        const ushort* p = &lds[b][0][aoff + half * 2048];  // +64 rows
#pragma unroll
        for (int i = 0; i < 4; ++i) af[i] = *(const short8*)(p + i * 512);
    };
    auto readB = [&](int b) {
        const ushort* p = &lds[b][1][boff];
#pragma unroll
        for (int j = 0; j < 4; ++j) bf[j] = *(const short8*)(p + j * 512);
    };
    auto mma = [&](int half) {
        __builtin_amdgcn_s_setprio(1);
#pragma unroll
        for (int i = 0; i < 4; ++i)
#pragma unroll
            for (int j = 0; j < 4; ++j)
                acc[half * 4 + i][j] =
                    __builtin_amdgcn_mfma_f32_16x16x32_bf16(af[i], bf[j], acc[half * 4 + i][j], 0, 0, 0);
        __builtin_amdgcn_s_setprio(0);
    };

    int NT = K >> 5;                           // K-tiles of 32 (>= 4 for all uses)
    // prologue: stage tiles 0,1,2 (12 loads); gate tile 0; barrier
    stageA(0, 0);  stageB(0, 0);
    stageA(1, 32); stageB(1, 32);
    stageA(2, 64); stageB(2, 64);
    asm volatile("s_waitcnt vmcnt(8)" ::: "memory");
    __builtin_amdgcn_s_barrier();

    for (int t = 0; t < NT; ++t) {
        int b = t & 3;
        // ---- Phase 1 ----
        readA(b, 0); readB(b);
        if (t + 3 < NT) stageA((t + 3) & 3, (t + 3) << 5);
        __builtin_amdgcn_s_barrier();
        asm volatile("s_waitcnt lgkmcnt(0)" ::: "memory");
        __builtin_amdgcn_sched_barrier(0);
        mma(0);
        __builtin_amdgcn_s_barrier();
        // ---- Phase 2 ----
        readA(b, 1);
        if (t + 3 < NT) {
            stageB((t + 3) & 3, (t + 3) << 5);
            asm volatile("s_waitcnt vmcnt(8)" ::: "memory");   // t+1 landed; t+2,t+3 in flight
        } else if (t + 2 < NT) {
            asm volatile("s_waitcnt vmcnt(4)" ::: "memory");   // drain: t+1 landed
        } else if (t + 1 < NT) {
            asm volatile("s_waitcnt vmcnt(0)" ::: "memory");   // drain: last tile landed
        }
        __builtin_amdgcn_s_barrier();
        asm volatile("s_waitcnt lgkmcnt(0)" ::: "memory");
        __builtin_amdgcn_sched_barrier(0);
        mma(1);
        __builtin_amdgcn_s_barrier();
    }

    if (MODE == 5) {
        // direct f32 stores + bias: 16 lanes cover 16 consecutive n -> 64B lines
        float* Cf = (float*)C + (long long)nt * 524288;
#pragma unroll
        for (int i = 0; i < 8; ++i) {
            int m = m0 + wr * 128 + i * 16 + quad * 4;
#pragma unroll
            for (int j = 0; j < 4; ++j) {
                int n = wc * 64 + j * 16 + l16;
                float* dst = Cf + (long long)m * 256 + n;
#pragma unroll
                for (int r = 0; r < 4; ++r)
                    dst[(long)r * 256] = acc[i][j][r] + bias0[m + r];
            }
        }
        return;
    }

    if (MODE == 4) {
        int sec = m0 >> 11;                    // block-uniform: 0=q, 1=k, 2=v
        int ms0 = m0 & 2047;
        ushort* ct = &lds[0][0][0];            // re-tile buffer: 128 x 264 ushorts
        if (sec < 2) {
            const float* bs = (sec == 0) ? bias0 : bias1;
            ushort* base = (ushort*)C + (long long)sec * 16777216
                         + (long long)nt * 524288 + (long long)(ms0 >> 8) * 65536;
#pragma unroll
            for (int hh = 0; hh < 2; ++hh) {   // n-halves; waves wc>>1==hh own half
                if ((wc >> 1) == hh) {
#pragma unroll
                    for (int i = 0; i < 8; ++i)
#pragma unroll
                        for (int j = 0; j < 4; ++j) {
                            int nl = (wc & 1) * 64 + j * 16 + l16;
                            int ml = wr * 128 + i * 16 + quad * 4;
                            ushort4v pk;
#pragma unroll
                            for (int r = 0; r < 4; ++r)
                                pk[r] = f2bf(acc[i][j][r] + bs[ms0 + ml + r]);
                            *(ushort4v*)(ct + nl * 264 + ml) = pk;
                        }
                }
                __syncthreads();
                int row = tid & 127, c0 = (tid >> 7) * 64;
                ushort* dst = base + (long long)(hh * 128 + row) * 256 + c0;
                const ushort* src = ct + row * 264 + c0;
#pragma unroll
                for (int u = 0; u < 8; ++u)
                    *(ushort8*)(dst + u * 8) = *(const ushort8*)(src + u * 8);
                __syncthreads();
            }
        } else {
            ushort* base = (ushort*)C + 33554432LL + (long long)nt * 524288
                         + (long long)ms0 * 256;
#pragma unroll
            for (int hh = 0; hh < 2; ++hh) {   // m-halves; waves wr==hh own half
                if (wr == hh) {
#pragma unroll
                    for (int i = 0; i < 8; ++i)
#pragma unroll
                        for (int j = 0; j < 4; ++j) {
                            int nl = wc * 64 + j * 16 + l16;
                            int ml = i * 16 + quad * 4;
#pragma unroll
                            for (int r = 0; r < 4; ++r)
                                ct[(ml + r) * 264 + nl] =
                                    f2bf(acc[i][j][r] + bias2[ms0 + hh * 128 + ml + r]);
                        }
                }
                __syncthreads();
                int row = tid & 127, c0 = (tid >> 7) * 64;
                ushort* dst = base + (long long)(hh * 128 + row) * 256 + c0;
                const ushort* src = ct + row * 264 + c0;
#pragma unroll
                for (int u = 0; u < 8; ++u)
                    *(ushort8*)(dst + u * 8) = *(const ushort8*)(src + u * 8);
                __syncthreads();
            }
        }
        return;
    }
}

// ---------------- T = (Q^T K~)/s with fused softmax -> P bf16 [z][n][p] ------------
// block: 128 n-rows x full 256 p-cols; waves 2x2 (wrow: n-half, wcol: p-half)
__global__ __launch_bounds__(256)
void tsm_kernel(const ushort* __restrict__ Q, const ushort* __restrict__ Kt,
                ushort* __restrict__ P, const float* __restrict__ scale_src)
{
    int z = blockIdx.y;
    const ushort* Ab = Q + (long)z * 65536;    // [n][d]
    const ushort* Bb = Kt + (long)z * 65536;   // [p][d]
    int n0 = blockIdx.x * 128;

    __shared__ __align__(16) ushort As[128 * 32];
    __shared__ __align__(16) ushort Bs[256 * 32];
    __shared__ float rmax[2][128];
    __shared__ float rsum[2][128];

    int tid = threadIdx.x;
    int wave = tid >> 6, lane = tid & 63;
    int wrow = wave >> 1, wcol = wave & 1;
    int l16 = lane & 15, quad = lane >> 4;
    int lrow = lane >> 2, lkq = lane & 3;

    fx4 acc[4][8];
#pragma unroll
    for (int i = 0; i < 4; ++i)
#pragma unroll
        for (int j = 0; j < 8; ++j) acc[i][j] = (fx4){0.f, 0.f, 0.f, 0.f};

    const ushort* gA0 = Ab + (long)(n0 + wave * 16 + lrow) * 256 + lkq * 8;
    const ushort* gA1 = gA0 + 64 * 256;
    const ushort* gB0 = Bb + (long)(wave * 16 + lrow) * 256 + lkq * 8;
    ushort* lA0 = As + (wave * 16) * 32;
    ushort* lA1 = As + (64 + wave * 16) * 32;
    ushort* lB0 = Bs + (wave * 16) * 32;

    for (int kc = 0; kc < 256; kc += 32) {
        __syncthreads();
        gload_lds16(gA0 + kc, lA0);
        gload_lds16(gA1 + kc, lA1);
        gload_lds16(gB0 + kc, lB0);
        gload_lds16(gB0 + 64 * 256 + kc, lB0 + 64 * 32);
        gload_lds16(gB0 + 128 * 256 + kc, lB0 + 128 * 32);
        gload_lds16(gB0 + 192 * 256 + kc, lB0 + 192 * 32);
        __syncthreads();

        short8 af[4], bf[8];
#pragma unroll
        for (int i = 0; i < 4; ++i)
            af[i] = *(const short8*)(As + (wrow * 64 + i * 16 + l16) * 32 + quad * 8);
#pragma unroll
        for (int j = 0; j < 8; ++j)
            bf[j] = *(const short8*)(Bs + (wcol * 128 + j * 16 + l16) * 32 + quad * 8);
#pragma unroll
        for (int i = 0; i < 4; ++i)
#pragma unroll
            for (int j = 0; j < 8; ++j)
                acc[i][j] = __builtin_amdgcn_mfma_f32_16x16x32_bf16(af[i], bf[j], acc[i][j], 0, 0, 0);
    }

    float sc = 1.0f / scale_src[0];
#pragma unroll
    for (int i = 0; i < 4; ++i)
#pragma unroll
        for (int j = 0; j < 8; ++j)
#pragma unroll
            for (int r = 0; r < 4; ++r) acc[i][j][r] *= sc;

    // --- row max: local over j, shfl over l16 (16-lane groups), LDS over wcol ---
    float lm[4][4];
#pragma unroll
    for (int i = 0; i < 4; ++i)
#pragma unroll
        for (int r = 0; r < 4; ++r) {
            float m = -1e30f;
#pragma unroll
            for (int j = 0; j < 8; ++j) m = fmaxf(m, acc[i][j][r]);
            lm[i][r] = m;
        }
#pragma unroll
    for (int d = 1; d < 16; d <<= 1)
#pragma unroll
        for (int i = 0; i < 4; ++i)
#pragma unroll
            for (int r = 0; r < 4; ++r) lm[i][r] = fmaxf(lm[i][r], __shfl_xor(lm[i][r], d, 16));
    if (l16 == 0) {
#pragma unroll
        for (int i = 0; i < 4; ++i)
#pragma unroll
            for (int r = 0; r < 4; ++r)
                rmax[wcol][wrow * 64 + i * 16 + quad * 4 + r] = lm[i][r];
    }
    __syncthreads();

    // --- exp + row sum ---
    float ls[4][4];
#pragma unroll
    for (int i = 0; i < 4; ++i)
#pragma unroll
        for (int r = 0; r < 4; ++r) {
            int row = wrow * 64 + i * 16 + quad * 4 + r;
            float M = fmaxf(rmax[0][row], rmax[1][row]);
            float s = 0.f;
#pragma unroll
            for (int j = 0; j < 8; ++j) {
                float e = __expf(acc[i][j][r] - M);
                acc[i][j][r] = e;
                s += e;
            }
            ls[i][r] = s;
        }
#pragma unroll
    for (int d = 1; d < 16; d <<= 1)
#pragma unroll
        for (int i = 0; i < 4; ++i)
#pragma unroll
            for (int r = 0; r < 4; ++r) ls[i][r] += __shfl_xor(ls[i][r], d, 16);
    if (l16 == 0) {
#pragma unroll
        for (int i = 0; i < 4; ++i)
#pragma unroll
            for (int r = 0; r < 4; ++r)
                rsum[wcol][wrow * 64 + i * 16 + quad * 4 + r] = ls[i][r];
    }
    __syncthreads();

    // --- normalize + write P ---
    ushort* Pb = P + (long)z * 65536;
#pragma unroll
    for (int i = 0; i < 4; ++i)
#pragma unroll
        for (int r = 0; r < 4; ++r) {
            int row = wrow * 64 + i * 16 + quad * 4 + r;
            float inv = 1.0f / (rsum[0][row] + rsum[1][row]);
#pragma unroll
            for (int j = 0; j < 8; ++j)
                Pb[(long)(n0 + row) * 256 + wcol * 128 + j * 16 + l16] = f2bf(acc[i][j][r] * inv);
        }
}

extern "C" void kernel_launch(void* const* d_in, const int* in_sizes, int n_in,
                              void* d_out, int out_size, void* d_ws, size_t ws_size,
                              hipStream_t stream)
{
    const float* x     = (const float*)d_in[0];
    const float* Wq    = (const float*)d_in[1];
    const float* bq    = (const float*)d_in[2];
    const float* Wk    = (const float*)d_in[3];
    const float* bk    = (const float*)d_in[4];
    const float* Wv    = (const float*)d_in[5];
    const float* bv    = (const float*)d_in[6];
    const float* Wo    = (const float*)d_in[7];
    const float* bo    = (const float*)d_in[8];
    const float* coeff = (const float*)d_in[9];
    const float* scale = (const float*)d_in[10];
    float* out = (float*)d_out;

    size_t o = 0;
    char* w = (char*)d_ws;
    auto take = [&](size_t bytes) -> void* {
        void* p = w + o; o += (bytes + 255) & ~(size_t)255; return p;
    };
    int*    coo_cnt = (int*)take(4);
    int*    coo_m   = (int*)take(MAXNNZ * 4);
    int*    coo_p   = (int*)take(MAXNNZ * 4);
    float*  coo_v   = (float*)take(MAXNNZ * 4);
    int*    csc_ptr = (int*)take(257 * 4);
    int*    csc_m   = (int*)take(MAXNNZ * 4);
    float*  csc_v   = (float*)take(MAXNNZ * 4);
    ushort* wqkv = (ushort*)take(6144L * 512 * 2);       // [wq;wk;wv] stacked
    ushort* wob  = (ushort*)take(2048L * 2048 * 2);
    ushort* xT   = (ushort*)take(32L * 256 * 512 * 2);   // [b][n][cin] == [8192][512]
    ushort* qkv  = (ushort*)take(3 * 16777216L * 2);     // qbT | kbT | vb contiguous
    ushort* qbT = qkv;                                   // [b][h][n][d]
    ushort* kbT = qkv + 16777216L;                       // [b][h][m][d]
    ushort* vb  = qkv + 33554432L;                       // [b][2048][256]
    ushort* ktc = (ushort*)take(16777216L * 2);          // [z][p][d]
    // aliases (lifetimes disjoint):
    ushort* P_ws = kbT;   // kbT dead after kcomb; tsm writes P, PV reads it
    ushort* obT  = qbT;   // qbT dead after tsm; PV writes obT == [8192][2048], final reads
    (void)in_sizes; (void)n_in; (void)out_size; (void)ws_size;

    // 1) sparsity structure
    hipMemsetAsync(coo_cnt, 0, 4, stream);
    topk_kernel<<<256, 256, 0, stream>>>(coeff, coo_cnt, coo_m, coo_p, coo_v);
    csc_kernel<<<1, 256, 0, stream>>>(coo_cnt, coo_m, coo_p, coo_v, csc_ptr, csc_m, csc_v);

    // 2) weight converts + x transpose
    cvt4_kernel<<<dim3(1024, 4, 1), 256, 0, stream>>>(
        Wq, wqkv, 2048 * 512, Wk, wqkv + 2048L * 512, 2048 * 512,
        Wv, wqkv + 4096L * 512, 2048 * 512, Wo, wob, 2048 * 2048);
    transpose_f32_bf16<<<dim3(8, 4, 32), 256, 0, stream>>>(x, xT, 512, 256);

    // 3) merged QKV projection: [6144,512] x [8192,512]^T, 256^2 pipelined tiles
    gemm256<4><<<dim3(768, 1, 1), dim3(512, 1, 1), 0, stream>>>(
        wqkv, xT, qkv, bq, bk, bv, 24, 512);

    // 4) K-combine with sparse coeff: ktc[z][p][d]
    kcomb_kernel<<<dim3(4, 256), 256, 0, stream>>>(kbT, ktc, csc_ptr, csc_m, csc_v);

    // 5) T = (Q^T K~)/s, fused softmax -> P bf16 [z][n][p]
    tsm_kernel<<<dim3(2, 256), 256, 0, stream>>>(qbT, ktc, P_ws, scale);

    // 6) O[d][n] = sum_p V[d][p] P[n][p] -> obT [8192][2048]
    gemm128<3><<<dim3(2, 2, 256), 256, 0, stream>>>(
        vb, 65536, P_ws, 65536, obT, nullptr, nullptr, nullptr, 256, 256);

    // 7) merged final projection: [2048,2048] x [8192,2048]^T -> out f32 [b][2048][256]
    gemm256<5><<<dim3(256, 1, 1), dim3(512, 1, 1), 0, stream>>>(
        wob, obT, out, bo, nullptr, nullptr, 8, 2048);
}